// Round 1
// baseline (148.300 us; speedup 1.0000x reference)
//
#include <hip/hip_runtime.h>

#define B 4
#define C 256
#define CI 128
#define NPIX 3136      // 56*56, = 49 * 64
#define KSPLIT 7
#define BN_EPS_F 1e-5f

typedef float f4 __attribute__((ext_vector_type(4)));

// ---------------- s[b][c] = sum_n x[b][c][n] ----------------
__global__ __launch_bounds__(64) void rowsum_kernel(const float* __restrict__ x,
                                                    float* __restrict__ s) {
    int b = blockIdx.y, c = blockIdx.x;
    const float* row = x + ((size_t)(b * C + c)) * NPIX;
    float acc = 0.f;
    for (int n = threadIdx.x; n < NPIX; n += 64) acc += row[n];
#pragma unroll
    for (int off = 32; off > 0; off >>= 1) acc += __shfl_down(acc, off, 64);
    if (threadIdx.x == 0) s[b * C + c] = acc;
}

// ---------------- Gpart[ks][b][i][j] = sum_{n in chunk ks} x[b][i][n] x[b][j][n] ----
// grid (4, 4, B*KSPLIT), block 256. 64x64 tile, 4x4 acc per thread, f4 k-blocking.
__global__ __launch_bounds__(256) void xxt_kernel(const float* __restrict__ x,
                                                  float* __restrict__ Gp) {
    int j0 = blockIdx.x * 64, i0 = blockIdx.y * 64;
    int z = blockIdx.z;
    int b = z / KSPLIT, ks = z % KSPLIT;
    __shared__ float xi[64][68];
    __shared__ float xj[64][68];
    int tid = threadIdx.x;
    int tx = tid & 15, ty = tid >> 4;
    float acc[4][4] = {};
    const float* xb = x + (size_t)b * C * NPIX;
    for (int t = 0; t < KSPLIT; ++t) {
        int k0 = (ks * KSPLIT + t) * 64;
        __syncthreads();
#pragma unroll
        for (int l = 0; l < 4; ++l) {
            int idx = tid + l * 256;
            int r = idx >> 4, c4 = (idx & 15) << 2;
            *(f4*)&xi[r][c4] = *(const f4*)&xb[(size_t)(i0 + r) * NPIX + k0 + c4];
            *(f4*)&xj[r][c4] = *(const f4*)&xb[(size_t)(j0 + r) * NPIX + k0 + c4];
        }
        __syncthreads();
        for (int kk = 0; kk < 64; kk += 4) {
            f4 a[4], bb[4];
#pragma unroll
            for (int ii = 0; ii < 4; ++ii) a[ii] = *(const f4*)&xi[ty + 16 * ii][kk];
#pragma unroll
            for (int jj = 0; jj < 4; ++jj) bb[jj] = *(const f4*)&xj[tx + 16 * jj][kk];
#pragma unroll
            for (int q = 0; q < 4; ++q)
#pragma unroll
                for (int ii = 0; ii < 4; ++ii)
#pragma unroll
                    for (int jj = 0; jj < 4; ++jj)
                        acc[ii][jj] += a[ii][q] * bb[jj][q];
        }
    }
    float* Gb = Gp + ((size_t)(ks * B + b)) * C * C;
#pragma unroll
    for (int ii = 0; ii < 4; ++ii)
#pragma unroll
        for (int jj = 0; jj < 4; ++jj)
            Gb[(i0 + ty + 16 * ii) * C + (j0 + tx + 16 * jj)] = acc[ii][jj];
}

// ---------------- G = sum_ks Gpart ----------------
__global__ __launch_bounds__(256) void greduce_kernel(const float* __restrict__ Gp,
                                                      float* __restrict__ G) {
    int gid = blockIdx.x * 256 + threadIdx.x;
    float acc = 0.f;
#pragma unroll
    for (int ks = 0; ks < KSPLIT; ++ks) acc += Gp[(size_t)ks * (B * C * C) + gid];
    G[gid] = acc;
}

// ---------------- u = Wphi s ; v = Wg s (per batch) ----------------
__global__ __launch_bounds__(256) void uv_kernel(const float* __restrict__ wphi,
                                                 const float* __restrict__ wg,
                                                 const float* __restrict__ s,
                                                 float* __restrict__ u,
                                                 float* __restrict__ v) {
    int b = blockIdx.x;
    __shared__ float sl[C];
    for (int i = threadIdx.x; i < C; i += 256) sl[i] = s[b * C + i];
    __syncthreads();
    int t = threadIdx.x;
    const float* wrow = (t < CI) ? (wphi + t * C) : (wg + (t - CI) * C);
    float acc = 0.f;
    for (int c = 0; c < C; ++c) acc += wrow[c] * sl[c];
    if (t < CI) u[b * CI + t] = acc;
    else        v[b * CI + (t - CI)] = acc;
}

// ---------------- P[b][i][j] = sum_c Wphi[i][c] G[b][c][j] ----------------
__global__ __launch_bounds__(256) void pmat_kernel(const float* __restrict__ wphi,
                                                   const float* __restrict__ G,
                                                   float* __restrict__ P) {
    int gid = blockIdx.x * 256 + threadIdx.x;   // B*CI*C = 131072
    int b = gid >> 15;
    int i = (gid >> 8) & 127;
    int j = gid & 255;
    const float* wr = wphi + i * C;
    const float* Gb = G + (size_t)b * C * C;
    float acc = 0.f;
    for (int c = 0; c < C; ++c) acc += wr[c] * Gb[c * C + j];
    P[gid] = acc;
}

// ---------------- M[b][i][j] = (P Wg^T + u bg^T + bphi v^T)/N + bphi bg^T --------
__global__ __launch_bounds__(256) void mmat_kernel(const float* __restrict__ P,
                                                   const float* __restrict__ wg,
                                                   const float* __restrict__ u,
                                                   const float* __restrict__ v,
                                                   const float* __restrict__ bphi,
                                                   const float* __restrict__ bg,
                                                   float* __restrict__ M) {
    int gid = blockIdx.x * 256 + threadIdx.x;   // B*CI*CI = 65536
    int b = gid >> 14;
    int i = (gid >> 7) & 127;
    int j = gid & 127;
    const float* Pr = P + ((size_t)b * CI + i) * C;
    const float* wr = wg + j * C;
    float acc = 0.f;
    for (int c = 0; c < C; ++c) acc += Pr[c] * wr[c];
    const float invN = 1.0f / (float)NPIX;
    M[gid] = invN * (acc + u[b * CI + i] * bg[j] + bphi[i] * v[b * CI + j])
             + bphi[i] * bg[j];
}

// ---------------- A[b][o][i] = sum_j w_rec[o][j] M[b][i][j] ----------------
__global__ __launch_bounds__(256) void amat_kernel(const float* __restrict__ wrec,
                                                   const float* __restrict__ M,
                                                   float* __restrict__ A) {
    int gid = blockIdx.x * 256 + threadIdx.x;   // B*C*CI = 131072
    int b = gid >> 15;
    int o = (gid >> 7) & 255;
    int i = gid & 127;
    const float* wr = wrec + o * CI;
    const float* Mb = M + (size_t)b * CI * CI;
    float acc = 0.f;
    for (int j = 0; j < CI; ++j) acc += wr[j] * Mb[i * CI + j];
    A[gid] = acc;
}

// ---------------- bias5[b][o] = inv*(A btheta + b_rec) + beta - mean*inv ----------
__global__ __launch_bounds__(256) void bias_kernel(const float* __restrict__ A,
                                                   const float* __restrict__ btheta,
                                                   const float* __restrict__ brec,
                                                   const float* __restrict__ gamma,
                                                   const float* __restrict__ beta,
                                                   const float* __restrict__ mean,
                                                   const float* __restrict__ var,
                                                   float* __restrict__ bias5) {
    int b = blockIdx.x, o = threadIdx.x;
    const float* Ar = A + ((size_t)b * C + o) * CI;
    float acc = 0.f;
    for (int i = 0; i < CI; ++i) acc += Ar[i] * btheta[i];
    float inv = gamma[o] * rsqrtf(var[o] + BN_EPS_F);
    bias5[b * C + o] = inv * (acc + brec[o]) + beta[o] - mean[o] * inv;
}

// ---------------- W5[b][o][c] = inv[o] * sum_i A[b][o][i] Wtheta[i][c] ------------
__global__ __launch_bounds__(256) void w5_kernel(const float* __restrict__ A,
                                                 const float* __restrict__ wtheta,
                                                 const float* __restrict__ gamma,
                                                 const float* __restrict__ var,
                                                 float* __restrict__ W5) {
    int gid = blockIdx.x * 256 + threadIdx.x;   // B*C*C = 262144
    int b = gid >> 16;
    int o = (gid >> 8) & 255;
    int c = gid & 255;
    const float* Ar = A + ((size_t)b * C + o) * CI;
    float acc = 0.f;
    for (int i = 0; i < CI; ++i) acc += Ar[i] * wtheta[i * C + c];
    float inv = gamma[o] * rsqrtf(var[o] + BN_EPS_F);
    W5[gid] = inv * acc;
}

// ---------------- out[b][o][n] = sum_c W5[b][o][c] x[b][c][n] + bias5 + x[b][o][n]-
// grid (NPIX/64, C/64, B), block 256. 64x64 tile, K=256 in 4 chunks of 64.
__global__ __launch_bounds__(256) void final_kernel(const float* __restrict__ x,
                                                    const float* __restrict__ W5,
                                                    const float* __restrict__ bias5,
                                                    float* __restrict__ out) {
    int b = blockIdx.z;
    int o0 = blockIdx.y * 64, n0 = blockIdx.x * 64;
    __shared__ float wl[64][68];   // [o_local][k]
    __shared__ float xl[64][68];   // [k_local][n_local]
    int tid = threadIdx.x;
    int tx = tid & 15, ty = tid >> 4;
    float acc[4][4] = {};
    const float* W5b = W5 + (size_t)b * C * C;
    const float* xb = x + (size_t)b * C * NPIX;
    for (int k0 = 0; k0 < C; k0 += 64) {
        __syncthreads();
#pragma unroll
        for (int l = 0; l < 4; ++l) {
            int idx = tid + l * 256;
            int r = idx >> 4, c4 = (idx & 15) << 2;
            *(f4*)&wl[r][c4] = *(const f4*)&W5b[(o0 + r) * C + k0 + c4];
            *(f4*)&xl[r][c4] = *(const f4*)&xb[(size_t)(k0 + r) * NPIX + n0 + c4];
        }
        __syncthreads();
        for (int kk = 0; kk < 64; kk += 4) {
            f4 a[4], bb[4];
#pragma unroll
            for (int i = 0; i < 4; ++i) a[i] = *(const f4*)&wl[ty + 16 * i][kk];
#pragma unroll
            for (int q = 0; q < 4; ++q) bb[q] = *(const f4*)&xl[kk + q][tx * 4];
#pragma unroll
            for (int q = 0; q < 4; ++q)
#pragma unroll
                for (int i = 0; i < 4; ++i)
#pragma unroll
                    for (int j = 0; j < 4; ++j)
                        acc[i][j] += a[i][q] * bb[q][j];
        }
    }
#pragma unroll
    for (int i = 0; i < 4; ++i) {
        int o = o0 + ty + 16 * i;
        float bias = bias5[b * C + o];
        int n = n0 + tx * 4;
        const f4 xr = *(const f4*)&xb[(size_t)o * NPIX + n];
        f4 r;
#pragma unroll
        for (int j = 0; j < 4; ++j) r[j] = acc[i][j] + bias + xr[j];
        *(f4*)&out[((size_t)b * C + o) * NPIX + n] = r;
    }
}

extern "C" void kernel_launch(void* const* d_in, const int* in_sizes, int n_in,
                              void* d_out, int out_size, void* d_ws, size_t ws_size,
                              hipStream_t stream) {
    const float* x       = (const float*)d_in[0];
    const float* w_theta = (const float*)d_in[1];
    const float* b_theta = (const float*)d_in[2];
    const float* w_phi   = (const float*)d_in[3];
    const float* b_phi   = (const float*)d_in[4];
    const float* w_g     = (const float*)d_in[5];
    const float* b_g     = (const float*)d_in[6];
    const float* w_rec   = (const float*)d_in[7];
    const float* b_rec   = (const float*)d_in[8];
    const float* gamma   = (const float*)d_in[9];
    const float* beta    = (const float*)d_in[10];
    const float* mean    = (const float*)d_in[11];
    const float* var     = (const float*)d_in[12];
    float* out = (float*)d_out;

    // Scratch consumed BEFORE final_kernel writes d_out lives in d_out;
    // W5/bias5 (read concurrently with out-writes) live in d_ws (~1.04 MB needed).
    float* Gp    = out;                       // 7*4*256*256 = 1,835,008 floats
    float* G     = out + 1835008;             // 262,144
    float* P     = out + 2097152;             // 131,072
    float* M     = out + 2228224;             // 65,536
    float* A     = out + 2293760;             // 131,072  (ends 2,424,832 < 3,211,264)
    float* ws    = (float*)d_ws;
    float* s     = ws;                        // 1024
    float* u     = ws + 1024;                 // 512
    float* v     = ws + 1536;                 // 512
    float* bias5 = ws + 2048;                 // 1024
    float* W5    = ws + 3072;                 // 262,144

    rowsum_kernel<<<dim3(C, B), dim3(64), 0, stream>>>(x, s);
    xxt_kernel<<<dim3(4, 4, B * KSPLIT), dim3(256), 0, stream>>>(x, Gp);
    greduce_kernel<<<dim3(B * C * C / 256), dim3(256), 0, stream>>>(Gp, G);
    uv_kernel<<<dim3(B), dim3(256), 0, stream>>>(w_phi, w_g, s, u, v);
    pmat_kernel<<<dim3(B * CI * C / 256), dim3(256), 0, stream>>>(w_phi, G, P);
    mmat_kernel<<<dim3(B * CI * CI / 256), dim3(256), 0, stream>>>(P, w_g, u, v, b_phi, b_g, M);
    amat_kernel<<<dim3(B * C * CI / 256), dim3(256), 0, stream>>>(w_rec, M, A);
    bias_kernel<<<dim3(B), dim3(256), 0, stream>>>(A, b_theta, b_rec, gamma, beta, mean, var, bias5);
    w5_kernel<<<dim3(B * C * C / 256), dim3(256), 0, stream>>>(A, w_theta, gamma, var, W5);
    final_kernel<<<dim3(NPIX / 64, C / 64, B), dim3(256), 0, stream>>>(x, W5, bias5, out);
}

// Round 2
// 124.345 us; speedup vs baseline: 1.1927x; 1.1927x over previous
//
#include <hip/hip_runtime.h>

#define B 4
#define C 256
#define CI 128
#define NPIX 3136      // 56*56 = 49 * 64
#define KS 7           // split-K for xxt: 7 chunks of 448 (=14 mfma steps)
#define BN_EPS_F 1e-5f

typedef float f4 __attribute__((ext_vector_type(4)));
typedef float f32x4 __attribute__((ext_vector_type(4)));
typedef short short8 __attribute__((ext_vector_type(8)));
typedef short short4v __attribute__((ext_vector_type(4)));

__device__ inline short f2bf(float f) {
    unsigned u = __builtin_bit_cast(unsigned, f);
    unsigned r = (u + 0x7FFFu + ((u >> 16) & 1u)) >> 16;
    return (short)r;
}

// ---------------- s[b][c] = sum_n x[b][c][n] ----------------
__global__ __launch_bounds__(64) void rowsum_kernel(const float* __restrict__ x,
                                                    float* __restrict__ s) {
    int b = blockIdx.y, c = blockIdx.x;
    const float* row = x + ((size_t)(b * C + c)) * NPIX;
    float acc = 0.f;
    for (int n = threadIdx.x; n < NPIX; n += 64) acc += row[n];
#pragma unroll
    for (int off = 32; off > 0; off >>= 1) acc += __shfl_down(acc, off, 64);
    if (threadIdx.x == 0) s[b * C + c] = acc;
}

// ---------------- xbf[b][c][n] = bf16(x); xT[b][n][c] = bf16(x) ----------------
// grid (49, 4, B), block 256. 64x64 tile transpose through LDS.
__global__ __launch_bounds__(256) void prep_kernel(const float* __restrict__ x,
                                                   short* __restrict__ xbf,
                                                   short* __restrict__ xT) {
    int b = blockIdx.z, c0 = blockIdx.y * 64, n0 = blockIdx.x * 64;
    __shared__ short lds[64][65];   // [n_local][c_local]
    int t = threadIdx.x;
    int nf = (t & 15) * 4;
    int cr = t >> 4;
#pragma unroll
    for (int it = 0; it < 4; ++it) {
        int c = cr + 16 * it;
        f4 v = *(const f4*)&x[((size_t)(b * C + c0 + c)) * NPIX + n0 + nf];
        short4v s4;
#pragma unroll
        for (int i = 0; i < 4; ++i) s4[i] = f2bf(v[i]);
        *(short4v*)&xbf[((size_t)(b * C + c0 + c)) * NPIX + n0 + nf] = s4;
#pragma unroll
        for (int i = 0; i < 4; ++i) lds[nf + i][c] = s4[i];
    }
    __syncthreads();
#pragma unroll
    for (int it = 0; it < 4; ++it) {
        int n = cr + 16 * it;
        short4v s4;
#pragma unroll
        for (int i = 0; i < 4; ++i) s4[i] = lds[n][nf + i];
        *(short4v*)&xT[((size_t)b * NPIX + n0 + n) * C + c0 + nf] = s4;
    }
}

// ---------------- Gpart[ks][b][i][j] = sum_{n in chunk} x[b][i][n] x[b][j][n] ----
// MFMA version. grid (2, 2, B*KS), block 256 (4 waves, 2x2 of 64x64).
// Fragments loaded straight from global (L2-resident); A and B use the
// identical lane->k mapping so the result is k-permutation invariant.
__global__ __launch_bounds__(256) void xxt_mfma(const short* __restrict__ xbf,
                                                float* __restrict__ Gp) {
    int z = blockIdx.z;
    int b = z / KS, ks = z % KS;
    int tid = threadIdx.x, lane = tid & 63, wid = tid >> 6;
    int ibase = blockIdx.y * 128 + (wid >> 1) * 64;
    int jbase = blockIdx.x * 128 + (wid & 1) * 64;
    int lm = lane & 15, lk = (lane >> 4) * 8;
    const short* A0 = xbf + ((size_t)(b * C) + ibase + lm) * NPIX + lk;
    const short* B0 = xbf + ((size_t)(b * C) + jbase + lm) * NPIX + lk;
    f32x4 acc[4][4] = {};
    int kend = ks * 448 + 448;
    for (int k = ks * 448; k < kend; k += 32) {
        short8 a[4], bv[4];
#pragma unroll
        for (int mi = 0; mi < 4; ++mi) a[mi] = *(const short8*)(A0 + (size_t)mi * 16 * NPIX + k);
#pragma unroll
        for (int nj = 0; nj < 4; ++nj) bv[nj] = *(const short8*)(B0 + (size_t)nj * 16 * NPIX + k);
#pragma unroll
        for (int mi = 0; mi < 4; ++mi)
#pragma unroll
            for (int nj = 0; nj < 4; ++nj)
                acc[mi][nj] = __builtin_amdgcn_mfma_f32_16x16x32_bf16(a[mi], bv[nj], acc[mi][nj], 0, 0, 0);
    }
    float* out = Gp + ((size_t)(ks * B + b)) * C * C;
    int r0 = (lane >> 4) * 4;
#pragma unroll
    for (int mi = 0; mi < 4; ++mi)
#pragma unroll
        for (int r = 0; r < 4; ++r)
#pragma unroll
            for (int nj = 0; nj < 4; ++nj)
                out[(ibase + mi * 16 + r0 + r) * C + jbase + nj * 16 + lm] = acc[mi][nj][r];
}

// ---------------- G = sum_ks Gpart ----------------
__global__ __launch_bounds__(256) void greduce_kernel(const float* __restrict__ Gp,
                                                      float* __restrict__ G) {
    int gid = blockIdx.x * 256 + threadIdx.x;
    float acc = 0.f;
#pragma unroll
    for (int ks = 0; ks < KS; ++ks) acc += Gp[(size_t)ks * (B * C * C) + gid];
    G[gid] = acc;
}

// ---------------- u = Wphi s ; v = Wg s (per batch) ----------------
__global__ __launch_bounds__(256) void uv_kernel(const float* __restrict__ wphi,
                                                 const float* __restrict__ wg,
                                                 const float* __restrict__ s,
                                                 float* __restrict__ u,
                                                 float* __restrict__ v) {
    int b = blockIdx.x;
    __shared__ float sl[C];
    for (int i = threadIdx.x; i < C; i += 256) sl[i] = s[b * C + i];
    __syncthreads();
    int t = threadIdx.x;
    const float* wrow = (t < CI) ? (wphi + t * C) : (wg + (t - CI) * C);
    float acc = 0.f;
    for (int c = 0; c < C; ++c) acc += wrow[c] * sl[c];
    if (t < CI) u[b * CI + t] = acc;
    else        v[b * CI + (t - CI)] = acc;
}

// ---------------- P[b][i][j] = sum_c Wphi[i][c] G[b][c][j] ----------------
__global__ __launch_bounds__(256) void pmat_kernel(const float* __restrict__ wphi,
                                                   const float* __restrict__ G,
                                                   float* __restrict__ P) {
    int gid = blockIdx.x * 256 + threadIdx.x;   // B*CI*C = 131072
    int b = gid >> 15;
    int i = (gid >> 8) & 127;
    int j = gid & 255;
    const float* wr = wphi + i * C;
    const float* Gb = G + (size_t)b * C * C;
    float acc = 0.f;
    for (int c = 0; c < C; ++c) acc += wr[c] * Gb[c * C + j];
    P[gid] = acc;
}

// ---------------- M[b][i][j] = (P Wg^T + u bg^T + bphi v^T)/N + bphi bg^T --------
__global__ __launch_bounds__(256) void mmat_kernel(const float* __restrict__ P,
                                                   const float* __restrict__ wg,
                                                   const float* __restrict__ u,
                                                   const float* __restrict__ v,
                                                   const float* __restrict__ bphi,
                                                   const float* __restrict__ bg,
                                                   float* __restrict__ M) {
    int gid = blockIdx.x * 256 + threadIdx.x;   // B*CI*CI = 65536
    int b = gid >> 14;
    int i = (gid >> 7) & 127;
    int j = gid & 127;
    const float* Pr = P + ((size_t)b * CI + i) * C;
    const float* wr = wg + j * C;
    float acc = 0.f;
    for (int c = 0; c < C; ++c) acc += Pr[c] * wr[c];
    const float invN = 1.0f / (float)NPIX;
    M[gid] = invN * (acc + u[b * CI + i] * bg[j] + bphi[i] * v[b * CI + j])
             + bphi[i] * bg[j];
}

// ---------------- A[b][o][i] = sum_j w_rec[o][j] M[b][i][j] ----------------
__global__ __launch_bounds__(256) void amat_kernel(const float* __restrict__ wrec,
                                                   const float* __restrict__ M,
                                                   float* __restrict__ A) {
    int gid = blockIdx.x * 256 + threadIdx.x;   // B*C*CI = 131072
    int b = gid >> 15;
    int o = (gid >> 7) & 255;
    int i = gid & 127;
    const float* wr = wrec + o * CI;
    const float* Mb = M + (size_t)b * CI * CI;
    float acc = 0.f;
    for (int j = 0; j < CI; ++j) acc += wr[j] * Mb[i * CI + j];
    A[gid] = acc;
}

// ---------------- bias5[b][o] = inv*(A btheta + b_rec) + beta - mean*inv ----------
__global__ __launch_bounds__(256) void bias_kernel(const float* __restrict__ A,
                                                   const float* __restrict__ btheta,
                                                   const float* __restrict__ brec,
                                                   const float* __restrict__ gamma,
                                                   const float* __restrict__ beta,
                                                   const float* __restrict__ mean,
                                                   const float* __restrict__ var,
                                                   float* __restrict__ bias5) {
    int b = blockIdx.x, o = threadIdx.x;
    const float* Ar = A + ((size_t)b * C + o) * CI;
    float acc = 0.f;
    for (int i = 0; i < CI; ++i) acc += Ar[i] * btheta[i];
    float inv = gamma[o] * rsqrtf(var[o] + BN_EPS_F);
    bias5[b * C + o] = inv * (acc + brec[o]) + beta[o] - mean[o] * inv;
}

// ---------------- W5bf[b][o][c] = bf16(inv[o] * sum_i A[b][o][i] Wtheta[i][c]) ----
__global__ __launch_bounds__(256) void w5_kernel(const float* __restrict__ A,
                                                 const float* __restrict__ wtheta,
                                                 const float* __restrict__ gamma,
                                                 const float* __restrict__ var,
                                                 short* __restrict__ W5bf) {
    int gid = blockIdx.x * 256 + threadIdx.x;   // B*C*C = 262144
    int b = gid >> 16;
    int o = (gid >> 8) & 255;
    int c = gid & 255;
    const float* Ar = A + ((size_t)b * C + o) * CI;
    float acc = 0.f;
    for (int i = 0; i < CI; ++i) acc += Ar[i] * wtheta[i * C + c];
    float inv = gamma[o] * rsqrtf(var[o] + BN_EPS_F);
    W5bf[gid] = f2bf(inv * acc);
}

// ---------------- out[b][o][n] = sum_c W5[o][c] x[c][n] + bias5[o] + x[o][n] ------
// MFMA. grid (49, B), block 256 (4 waves, each 64 o x 64 n; block = 256 o x 64 n).
// A = W5bf [o][c] (c-contig), B = xT [n][c] (c-contig).
__global__ __launch_bounds__(256) void final_mfma(const float* __restrict__ x,
                                                  const short* __restrict__ W5bf,
                                                  const short* __restrict__ xT,
                                                  const float* __restrict__ bias5,
                                                  float* __restrict__ out) {
    int b = blockIdx.y;
    int n0 = blockIdx.x * 64;
    int tid = threadIdx.x, lane = tid & 63, wid = tid >> 6;
    int obase = wid * 64;
    int lm = lane & 15, lk = (lane >> 4) * 8;
    const short* A0 = W5bf + ((size_t)(b * C) + obase + lm) * C + lk;
    const short* B0 = xT + ((size_t)b * NPIX + n0 + lm) * C + lk;
    f32x4 acc[4][4] = {};
#pragma unroll
    for (int k = 0; k < C; k += 32) {
        short8 a[4], bv[4];
#pragma unroll
        for (int mi = 0; mi < 4; ++mi) a[mi] = *(const short8*)(A0 + mi * 16 * C + k);
#pragma unroll
        for (int nj = 0; nj < 4; ++nj) bv[nj] = *(const short8*)(B0 + nj * 16 * C + k);
#pragma unroll
        for (int mi = 0; mi < 4; ++mi)
#pragma unroll
            for (int nj = 0; nj < 4; ++nj)
                acc[mi][nj] = __builtin_amdgcn_mfma_f32_16x16x32_bf16(a[mi], bv[nj], acc[mi][nj], 0, 0, 0);
    }
    int r0 = (lane >> 4) * 4;
#pragma unroll
    for (int mi = 0; mi < 4; ++mi) {
#pragma unroll
        for (int r = 0; r < 4; ++r) {
            int o = obase + mi * 16 + r0 + r;
            float bias = bias5[b * C + o];
            const float* xrow = x + ((size_t)(b * C + o)) * NPIX;
            float* orow = out + ((size_t)(b * C + o)) * NPIX;
#pragma unroll
            for (int nj = 0; nj < 4; ++nj) {
                int n = n0 + nj * 16 + lm;
                orow[n] = acc[mi][nj][r] + bias + xrow[n];
            }
        }
    }
}

extern "C" void kernel_launch(void* const* d_in, const int* in_sizes, int n_in,
                              void* d_out, int out_size, void* d_ws, size_t ws_size,
                              hipStream_t stream) {
    const float* x       = (const float*)d_in[0];
    const float* w_theta = (const float*)d_in[1];
    const float* b_theta = (const float*)d_in[2];
    const float* w_phi   = (const float*)d_in[3];
    const float* b_phi   = (const float*)d_in[4];
    const float* w_g     = (const float*)d_in[5];
    const float* b_g     = (const float*)d_in[6];
    const float* w_rec   = (const float*)d_in[7];
    const float* b_rec   = (const float*)d_in[8];
    const float* gamma   = (const float*)d_in[9];
    const float* beta    = (const float*)d_in[10];
    const float* mean    = (const float*)d_in[11];
    const float* var     = (const float*)d_in[12];
    float* out = (float*)d_out;

    // Scratch consumed BEFORE final_mfma writes d_out lives in d_out.
    float* Gp = out;                          // 7*4*256*256 = 1,835,008 floats
    float* G  = out + 1835008;                // 262,144
    float* P  = out + 2097152;                // 131,072
    float* M  = out + 2228224;                // 65,536
    float* A  = out + 2293760;                // 131,072  (ends 2,424,832 < 3,211,264)

    char* wsb = (char*)d_ws;
    float* s     = (float*)(wsb + 0);         // 1024 f32
    float* u     = (float*)(wsb + 4096);      // 512
    float* v     = (float*)(wsb + 6144);      // 512
    float* bias5 = (float*)(wsb + 8192);      // 1024
    short* W5bf  = (short*)(wsb + 16384);     // 262,144 bf16 (512 KB)
    short* xbf   = (short*)(wsb + (1u << 20));   // [b][c][n] bf16, 6.42 MB
    short* xT    = (short*)(wsb + (8u << 20));   // [b][n][c] bf16, 6.42 MB

    rowsum_kernel<<<dim3(C, B), dim3(64), 0, stream>>>(x, s);
    prep_kernel<<<dim3(NPIX / 64, C / 64, B), dim3(256), 0, stream>>>(x, xbf, xT);
    xxt_mfma<<<dim3(2, 2, B * KS), dim3(256), 0, stream>>>(xbf, Gp);
    greduce_kernel<<<dim3(B * C * C / 256), dim3(256), 0, stream>>>(Gp, G);
    uv_kernel<<<dim3(B), dim3(256), 0, stream>>>(w_phi, w_g, s, u, v);
    pmat_kernel<<<dim3(B * CI * C / 256), dim3(256), 0, stream>>>(w_phi, G, P);
    mmat_kernel<<<dim3(B * CI * CI / 256), dim3(256), 0, stream>>>(P, w_g, u, v, b_phi, b_g, M);
    amat_kernel<<<dim3(B * C * CI / 256), dim3(256), 0, stream>>>(w_rec, M, A);
    bias_kernel<<<dim3(B), dim3(256), 0, stream>>>(A, b_theta, b_rec, gamma, beta, mean, var, bias5);
    w5_kernel<<<dim3(B * C * C / 256), dim3(256), 0, stream>>>(A, w_theta, gamma, var, W5bf);
    final_mfma<<<dim3(NPIX / 64, B), dim3(256), 0, stream>>>(x, W5bf, xT, bias5, out);
}